// Round 8
// baseline (62.849 us; speedup 1.0000x reference)
//
#include <hip/hip_runtime.h>

#define DIMV 96
#define NCH 24
constexpr int VOX = DIMV * DIMV * DIMV;          // 884736
constexpr int N_CUR = 150000;
constexpr int N_GLB = 200000;
constexpr int N_TGT_LOC = 100000;
constexpr int N_TGT_GLB = 120000;

// ---- output offsets (floats) ----
constexpr size_t OFF_COORDS = 0;
constexpr size_t OFF_CURVOL = 450000;                         // 150000*3
constexpr size_t OFF_GLBVOL = OFF_CURVOL + (size_t)VOX * NCH; // 21,683,664
constexpr size_t OFF_TGTVOL = OFF_GLBVOL + (size_t)VOX * NCH; // 42,917,328
constexpr size_t OFF_VALID  = OFF_TGTVOL + (size_t)VOX;       // 43,802,064
constexpr size_t OFF_VALIDT = OFF_VALID + N_GLB;              // 44,002,064

typedef float v4f __attribute__((ext_vector_type(4)));
typedef int   v4i __attribute__((ext_vector_type(4)));

constexpr int N_COORD4 = (N_CUR * 3) / 4;        // 112500 int4->float4 copies
constexpr int NV4_WS   = (3 * VOX) / 4;          // 663552 int4 stores to init winners

__device__ __forceinline__ int voxel_of(int x, int y, int z) {
    return (x * DIMV + y) * DIMV + z;
}

// Kernel I: workspace winner init (-1) + coords int4->float4 copy.
// PLAIN stores (R1: NT init of the atomic-hammered winner arrays cost ~20 us).
__global__ void __launch_bounds__(256) k_init(int* __restrict__ ws,
                                              const int* __restrict__ cur_coords,
                                              float* __restrict__ coords_out) {
    int i = blockIdx.x * blockDim.x + threadIdx.x;
    if (i < NV4_WS) {
        v4i m = {-1, -1, -1, -1};
        *((v4i*)ws + i) = m;
    } else if (i < NV4_WS + N_COORD4) {
        int j = i - NV4_WS;
        v4i c = *(const v4i*)(cur_coords + 4 * j);
        v4f f = {(float)c.x, (float)c.y, (float)c.z, (float)c.w};
        *((v4f*)coords_out + j) = f;
    }
}

// Kernel P: ALL point scatters in one launch (unchanged from R6/R7).
__global__ void k_points(const int* __restrict__ cur_coords,
                         const int* __restrict__ tgt_coords_g,
                         const int* __restrict__ tgt_coords_l,
                         const int* __restrict__ glb_coords,
                         const int* __restrict__ origin,
                         int* __restrict__ w_cur,
                         int* __restrict__ w_tgt,
                         int* __restrict__ w_glb,
                         float* __restrict__ validt_out) {
    int i = blockIdx.x * blockDim.x + threadIdx.x;
    if (i < N_CUR) {
        int x = cur_coords[3 * i], y = cur_coords[3 * i + 1], z = cur_coords[3 * i + 2];
        if ((unsigned)x < DIMV && (unsigned)y < DIMV && (unsigned)z < DIMV)
            atomicMax(&w_cur[voxel_of(x, y, z)], i);   // last-write-wins = max idx
    } else if (i < N_CUR + N_TGT_GLB) {
        int j = i - N_CUR;
        int x = tgt_coords_g[3 * j]     - origin[0];
        int y = tgt_coords_g[3 * j + 1] - origin[1];
        int z = tgt_coords_g[3 * j + 2] - origin[2];
        bool inb = (unsigned)x < DIMV && (unsigned)y < DIMV && (unsigned)z < DIMV;
        validt_out[j] = inb ? 1.0f : 0.0f;
        if (inb) atomicMax(&w_tgt[voxel_of(x, y, z)], j);
    } else if (i < N_CUR + N_TGT_GLB + N_TGT_LOC) {
        int j = i - N_CUR - N_TGT_GLB;
        int x = tgt_coords_l[3 * j], y = tgt_coords_l[3 * j + 1], z = tgt_coords_l[3 * j + 2];
        if ((unsigned)x < DIMV && (unsigned)y < DIMV && (unsigned)z < DIMV)
            atomicMax(&w_tgt[voxel_of(x, y, z)], j + N_TGT_GLB);
    } else if (i < N_CUR + N_TGT_GLB + N_TGT_LOC + N_GLB) {
        int j = i - N_CUR - N_TGT_GLB - N_TGT_LOC;
        int x = glb_coords[3 * j]     - origin[0];
        int y = glb_coords[3 * j + 1] - origin[1];
        int z = glb_coords[3 * j + 2] - origin[2];
        if ((unsigned)x < DIMV && (unsigned)y < DIMV && (unsigned)z < DIMV)
            atomicMax(&w_glb[voxel_of(x, y, z)], j);
    }
}

// Kernel C (R8): byte-disjoint {point-driven payload} + {masked default fill}
// in ONE dispatch. All heavy reads are LINEAR (values/tsdf read by point
// index); all scattered traffic is posted WRITES (no wave stalls, no HBM
// read/write turnaround from random reads in the stream).
//  seg B [0, N_GLB*6):           glb payload (scattered writes) + valid (q==0)
//  seg A [+N_CUR*6):             cur payload: linear value reads, scattered row writes
//  seg T [+220000):              tgt payload: linear tsdf reads, scattered 4B writes
//  seg F [+VOX*6):               default fill, exec-masked where payload owns bytes
constexpr int SEG_B = N_GLB * 6;                  // 1200000
constexpr int SEG_A = N_CUR * 6;                  //  900000
constexpr int SEG_T = N_TGT_GLB + N_TGT_LOC;      //  220000
constexpr int SEG_F = VOX * 6;                    // 5308416
constexpr int FILL_TOTAL = SEG_B + SEG_A + SEG_T + SEG_F;

__global__ void __launch_bounds__(256) k_fill_all(
                           const int* __restrict__ w_cur,
                           const int* __restrict__ w_glb,
                           const int* __restrict__ w_tgt,
                           const int* __restrict__ cur_coords,
                           const int* __restrict__ glb_coords,
                           const int* __restrict__ tgt_coords_g,
                           const int* __restrict__ tgt_coords_l,
                           const int* __restrict__ origin,
                           const float* __restrict__ cur_values,
                           const float* __restrict__ glb_values,
                           const float* __restrict__ glb_tsdf,   // [120000]
                           const float* __restrict__ loc_tsdf,   // [100000]
                           float* __restrict__ cur_out,
                           float* __restrict__ glb_out,
                           float* __restrict__ tgt_out,
                           float* __restrict__ valid_out) {
    int i = blockIdx.x * blockDim.x + threadIdx.x;
    if (i < SEG_B) {
        int p = i / 6, q = i - p * 6;
        int x = glb_coords[3 * p]     - origin[0];
        int y = glb_coords[3 * p + 1] - origin[1];
        int z = glb_coords[3 * p + 2] - origin[2];
        bool inb = (unsigned)x < DIMV && (unsigned)y < DIMV && (unsigned)z < DIMV;
        int cx = min(max(x, 0), DIMV - 1);
        int cy = min(max(y, 0), DIMV - 1);
        int cz = min(max(z, 0), DIMV - 1);
        int v = voxel_of(cx, cy, cz);
        bool occ = w_cur[v] >= 0;
        if (q == 0) valid_out[p] = (inb && occ) ? 1.0f : 0.0f;
        if (inb && occ && w_glb[v] == p)
            *(v4f*)(glb_out + (size_t)v * NCH + q * 4) =
                *(const v4f*)(glb_values + (size_t)p * NCH + q * 4);
    } else if (i < SEG_B + SEG_A) {
        int t = i - SEG_B;
        int p = t / 6, q = t - p * 6;
        int x = cur_coords[3 * p], y = cur_coords[3 * p + 1], z = cur_coords[3 * p + 2];
        if ((unsigned)x < DIMV && (unsigned)y < DIMV && (unsigned)z < DIMV) {
            int v = voxel_of(x, y, z);
            if (w_cur[v] == p)   // 92% of points win -> value reads ~linear
                *(v4f*)(cur_out + (size_t)v * NCH + q * 4) =
                    *(const v4f*)(cur_values + (size_t)p * NCH + q * 4);
        }
    } else if (i < SEG_B + SEG_A + SEG_T) {
        int j = i - SEG_B - SEG_A;
        if (j < N_TGT_GLB) {
            int x = tgt_coords_g[3 * j]     - origin[0];
            int y = tgt_coords_g[3 * j + 1] - origin[1];
            int z = tgt_coords_g[3 * j + 2] - origin[2];
            if ((unsigned)x < DIMV && (unsigned)y < DIMV && (unsigned)z < DIMV) {
                int v = voxel_of(x, y, z);
                if (w_tgt[v] == j) tgt_out[v] = glb_tsdf[j];
            }
        } else {
            int jj = j - N_TGT_GLB;
            int x = tgt_coords_l[3 * jj], y = tgt_coords_l[3 * jj + 1], z = tgt_coords_l[3 * jj + 2];
            if ((unsigned)x < DIMV && (unsigned)y < DIMV && (unsigned)z < DIMV) {
                int v = voxel_of(x, y, z);
                if (w_tgt[v] == j + N_TGT_GLB) tgt_out[v] = loc_tsdf[jj];
            }
        }
    } else if (i < FILL_TOTAL) {
        int c = i - SEG_B - SEG_A - SEG_T;
        int v = c / 6, q = c - v * 6;
        const v4f zero = (v4f){0.f, 0.f, 0.f, 0.f};

        int wc = w_cur[v];
        if (wc < 0)                      // payload owns occupied rows
            *(v4f*)(cur_out + (size_t)v * NCH + q * 4) = zero;

        int wg = w_glb[v];
        if (wc < 0 || wg < 0)            // payload written iff wc>=0 && wg>=0
            *(v4f*)(glb_out + (size_t)v * NCH + q * 4) = zero;

        if (q == 0 && w_tgt[v] < 0)
            tgt_out[v] = 1.0f;
    }
}

extern "C" void kernel_launch(void* const* d_in, const int* in_sizes, int n_in,
                              void* d_out, int out_size, void* d_ws, size_t ws_size,
                              hipStream_t stream) {
    const int*   cur_coords   = (const int*)d_in[0];
    const float* cur_values   = (const float*)d_in[1];
    const int*   glb_coords   = (const int*)d_in[2];
    const float* glb_values   = (const float*)d_in[3];
    const int*   tgt_coords_l = (const int*)d_in[4];
    const float* tgt_tsdf_l   = (const float*)d_in[5];
    const int*   tgt_coords_g = (const int*)d_in[6];
    const float* tgt_tsdf_g   = (const float*)d_in[7];
    const int*   rel_origin   = (const int*)d_in[8];

    float* out = (float*)d_out;
    int* w_cur = (int*)d_ws;         // [VOX] winner current (>=0 also = occupancy)
    int* w_glb = w_cur + VOX;        // [VOX] winner global (in-bounds, voxel-gated)
    int* w_tgt = w_glb + VOX;        // [VOX] winner target

    const int T = 256;
    auto blocks = [](int n) { return (n + 255) / 256; };

    // 1: winner init to -1 + coords copy (plain stores -> L2-resident winners)
    k_init<<<blocks(NV4_WS + N_COORD4), T, 0, stream>>>(
        (int*)d_ws, cur_coords, out + OFF_COORDS);

    // 2: ALL point scatters (cur, tgt-g + validt, tgt-l, glb in-bounds)
    k_points<<<blocks(N_CUR + N_TGT_GLB + N_TGT_LOC + N_GLB), T, 0, stream>>>(
        cur_coords, tgt_coords_g, tgt_coords_l, glb_coords, rel_origin,
        w_cur, w_tgt, w_glb, out + OFF_VALIDT);

    // 3: byte-disjoint payload + masked default fill (one dispatch)
    k_fill_all<<<blocks(FILL_TOTAL), T, 0, stream>>>(
        w_cur, w_glb, w_tgt, cur_coords, glb_coords, tgt_coords_g, tgt_coords_l,
        rel_origin, cur_values, glb_values, tgt_tsdf_g, tgt_tsdf_l,
        out + OFF_CURVOL, out + OFF_GLBVOL, out + OFF_TGTVOL, out + OFF_VALID);
}

// Round 9
// 61.570 us; speedup vs baseline: 1.0208x; 1.0208x over previous
//
#include <hip/hip_runtime.h>

#define DIMV 96
#define NCH 24
constexpr int VOX = DIMV * DIMV * DIMV;          // 884736
constexpr int N_CUR = 150000;
constexpr int N_GLB = 200000;
constexpr int N_TGT_LOC = 100000;
constexpr int N_TGT_GLB = 120000;

// ---- output offsets (floats) ----
constexpr size_t OFF_COORDS = 0;
constexpr size_t OFF_CURVOL = 450000;                         // 150000*3 (16B-aligned: 450000%4==0)
constexpr size_t OFF_GLBVOL = OFF_CURVOL + (size_t)VOX * NCH; // 21,683,664
constexpr size_t OFF_TGTVOL = OFF_GLBVOL + (size_t)VOX * NCH; // 42,917,328 (16B-aligned)
constexpr size_t OFF_VALID  = OFF_TGTVOL + (size_t)VOX;       // 43,802,064
constexpr size_t OFF_VALIDT = OFF_VALID + N_GLB;              // 44,002,064

typedef float v4f __attribute__((ext_vector_type(4)));
typedef int   v4i __attribute__((ext_vector_type(4)));

constexpr int N_COORD4 = (N_CUR * 3) / 4;        // 112500 int4->float4 copies
constexpr int NV4_WS   = (3 * VOX) / 4;          // 663552 int4 stores to init winners

__device__ __forceinline__ int voxel_of(int x, int y, int z) {
    return (x * DIMV + y) * DIMV + z;
}

// Kernel I: workspace winner init (-1) + coords int4->float4 copy.
// PLAIN stores (R1: NT init of the atomic-hammered winner arrays cost ~20 us).
// Must precede k_work's atomics -> separate dispatch.
__global__ void __launch_bounds__(256) k_init(int* __restrict__ ws,
                                              const int* __restrict__ cur_coords,
                                              float* __restrict__ coords_out) {
    int i = blockIdx.x * blockDim.x + threadIdx.x;
    if (i < NV4_WS) {
        v4i m = {-1, -1, -1, -1};
        *((v4i*)ws + i) = m;
    } else if (i < NV4_WS + N_COORD4) {
        int j = i - NV4_WS;
        v4i c = *(const v4i*)(cur_coords + 4 * j);
        v4f f = {(float)c.x, (float)c.y, (float)c.z, (float)c.w};
        *((v4f*)coords_out + j) = f;
    }
}

// Kernel W (R9): {point atomics ∥ dense default fill} in ONE dispatch.
// The two segments touch disjoint memory (workspace vs outputs) -> no
// ordering needed. Atomics at low block indices (latency-bound, overlap
// the stream's ramp); defaults are DENSE UNMASKED plain v4f stores
// (R8 post-mortem: masked streams pay partial-line RMW; dense wins).
//  seg P [0, 570000):    atomics: cur(150k) | tgt_g+validt(120k) | tgt_l(100k) | glb(200k)
//  seg Z [+Z4):          cur_out+glb_out contiguous zeros (169.9 MB)
//  seg O [+T4):          tgt_out ones (3.5 MB)
constexpr int P_TOTAL = N_CUR + N_TGT_GLB + N_TGT_LOC + N_GLB;   // 570000
constexpr int Z4 = (VOX * NCH * 2) / 4;           // 10,616,832 v4f chunks
constexpr int T4 = VOX / 4;                       //    221,184 v4f chunks
constexpr int WORK_TOTAL = P_TOTAL + Z4 + T4;

__global__ void __launch_bounds__(256) k_work(
                         const int* __restrict__ cur_coords,
                         const int* __restrict__ tgt_coords_g,
                         const int* __restrict__ tgt_coords_l,
                         const int* __restrict__ glb_coords,
                         const int* __restrict__ origin,
                         int* __restrict__ w_cur,
                         int* __restrict__ w_tgt,
                         int* __restrict__ w_glb,
                         float* __restrict__ validt_out,
                         float* __restrict__ vol_base,   // out+OFF_CURVOL (cur+glb contiguous)
                         float* __restrict__ tgt_out) {
    int i = blockIdx.x * blockDim.x + threadIdx.x;
    if (i < N_CUR) {
        int x = cur_coords[3 * i], y = cur_coords[3 * i + 1], z = cur_coords[3 * i + 2];
        if ((unsigned)x < DIMV && (unsigned)y < DIMV && (unsigned)z < DIMV)
            atomicMax(&w_cur[voxel_of(x, y, z)], i);   // last-write-wins = max idx
    } else if (i < N_CUR + N_TGT_GLB) {
        int j = i - N_CUR;
        int x = tgt_coords_g[3 * j]     - origin[0];
        int y = tgt_coords_g[3 * j + 1] - origin[1];
        int z = tgt_coords_g[3 * j + 2] - origin[2];
        bool inb = (unsigned)x < DIMV && (unsigned)y < DIMV && (unsigned)z < DIMV;
        validt_out[j] = inb ? 1.0f : 0.0f;
        if (inb) atomicMax(&w_tgt[voxel_of(x, y, z)], j);
    } else if (i < N_CUR + N_TGT_GLB + N_TGT_LOC) {
        int j = i - N_CUR - N_TGT_GLB;
        int x = tgt_coords_l[3 * j], y = tgt_coords_l[3 * j + 1], z = tgt_coords_l[3 * j + 2];
        if ((unsigned)x < DIMV && (unsigned)y < DIMV && (unsigned)z < DIMV)
            atomicMax(&w_tgt[voxel_of(x, y, z)], j + N_TGT_GLB);
    } else if (i < P_TOTAL) {
        int j = i - N_CUR - N_TGT_GLB - N_TGT_LOC;
        int x = glb_coords[3 * j]     - origin[0];
        int y = glb_coords[3 * j + 1] - origin[1];
        int z = glb_coords[3 * j + 2] - origin[2];
        if ((unsigned)x < DIMV && (unsigned)y < DIMV && (unsigned)z < DIMV)
            atomicMax(&w_glb[voxel_of(x, y, z)], j);   // occupancy gated in k_payload
    } else if (i < P_TOTAL + Z4) {
        int j = i - P_TOTAL;
        *((v4f*)vol_base + j) = (v4f){0.f, 0.f, 0.f, 0.f};
    } else if (i < WORK_TOTAL) {
        int j = i - P_TOTAL - Z4;
        *((v4f*)tgt_out + j) = (v4f){1.f, 1.f, 1.f, 1.f};
    }
}

// Kernel Y (R9): winner-overwrite payload. Ordered AFTER k_work, so it may
// freely overwrite default bytes (exact last-write-wins semantics, no
// masking). All heavy reads LINEAR in point index; scattered traffic is
// posted writes only. R8's tgt-local bug fixed: winner value == combined
// index j in both branches.
//  seg B [0, N_GLB*6):           glb payload + valid (q==0)
//  seg A [+N_CUR*6):             cur payload rows
//  seg T [+220000):              tgt payload singles
constexpr int SEG_B = N_GLB * 6;                  // 1200000
constexpr int SEG_A = N_CUR * 6;                  //  900000
constexpr int SEG_T = N_TGT_GLB + N_TGT_LOC;      //  220000
constexpr int PAYLOAD_TOTAL = SEG_B + SEG_A + SEG_T;

__global__ void __launch_bounds__(256) k_payload(
                           const int* __restrict__ w_cur,
                           const int* __restrict__ w_glb,
                           const int* __restrict__ w_tgt,
                           const int* __restrict__ cur_coords,
                           const int* __restrict__ glb_coords,
                           const int* __restrict__ tgt_coords_g,
                           const int* __restrict__ tgt_coords_l,
                           const int* __restrict__ origin,
                           const float* __restrict__ cur_values,
                           const float* __restrict__ glb_values,
                           const float* __restrict__ glb_tsdf,   // [120000]
                           const float* __restrict__ loc_tsdf,   // [100000]
                           float* __restrict__ cur_out,
                           float* __restrict__ glb_out,
                           float* __restrict__ tgt_out,
                           float* __restrict__ valid_out) {
    int i = blockIdx.x * blockDim.x + threadIdx.x;
    if (i < SEG_B) {
        int p = i / 6, q = i - p * 6;
        int x = glb_coords[3 * p]     - origin[0];
        int y = glb_coords[3 * p + 1] - origin[1];
        int z = glb_coords[3 * p + 2] - origin[2];
        bool inb = (unsigned)x < DIMV && (unsigned)y < DIMV && (unsigned)z < DIMV;
        int cx = min(max(x, 0), DIMV - 1);
        int cy = min(max(y, 0), DIMV - 1);
        int cz = min(max(z, 0), DIMV - 1);
        int v = voxel_of(cx, cy, cz);
        bool occ = w_cur[v] >= 0;
        if (q == 0) valid_out[p] = (inb && occ) ? 1.0f : 0.0f;
        if (inb && occ && w_glb[v] == p)
            *(v4f*)(glb_out + (size_t)v * NCH + q * 4) =
                *(const v4f*)(glb_values + (size_t)p * NCH + q * 4);
    } else if (i < SEG_B + SEG_A) {
        int t = i - SEG_B;
        int p = t / 6, q = t - p * 6;
        int x = cur_coords[3 * p], y = cur_coords[3 * p + 1], z = cur_coords[3 * p + 2];
        if ((unsigned)x < DIMV && (unsigned)y < DIMV && (unsigned)z < DIMV) {
            int v = voxel_of(x, y, z);
            if (w_cur[v] == p)   // 92% of points win -> value reads ~linear
                *(v4f*)(cur_out + (size_t)v * NCH + q * 4) =
                    *(const v4f*)(cur_values + (size_t)p * NCH + q * 4);
        }
    } else if (i < PAYLOAD_TOTAL) {
        int j = i - SEG_B - SEG_A;
        if (j < N_TGT_GLB) {
            int x = tgt_coords_g[3 * j]     - origin[0];
            int y = tgt_coords_g[3 * j + 1] - origin[1];
            int z = tgt_coords_g[3 * j + 2] - origin[2];
            if ((unsigned)x < DIMV && (unsigned)y < DIMV && (unsigned)z < DIMV) {
                int v = voxel_of(x, y, z);
                if (w_tgt[v] == j) tgt_out[v] = glb_tsdf[j];
            }
        } else {
            int jj = j - N_TGT_GLB;
            int x = tgt_coords_l[3 * jj], y = tgt_coords_l[3 * jj + 1], z = tgt_coords_l[3 * jj + 2];
            if ((unsigned)x < DIMV && (unsigned)y < DIMV && (unsigned)z < DIMV) {
                int v = voxel_of(x, y, z);
                if (w_tgt[v] == j) tgt_out[v] = loc_tsdf[jj];   // winner val == combined idx j
            }
        }
    }
}

extern "C" void kernel_launch(void* const* d_in, const int* in_sizes, int n_in,
                              void* d_out, int out_size, void* d_ws, size_t ws_size,
                              hipStream_t stream) {
    const int*   cur_coords   = (const int*)d_in[0];
    const float* cur_values   = (const float*)d_in[1];
    const int*   glb_coords   = (const int*)d_in[2];
    const float* glb_values   = (const float*)d_in[3];
    const int*   tgt_coords_l = (const int*)d_in[4];
    const float* tgt_tsdf_l   = (const float*)d_in[5];
    const int*   tgt_coords_g = (const int*)d_in[6];
    const float* tgt_tsdf_g   = (const float*)d_in[7];
    const int*   rel_origin   = (const int*)d_in[8];

    float* out = (float*)d_out;
    int* w_cur = (int*)d_ws;         // [VOX] winner current (>=0 also = occupancy)
    int* w_glb = w_cur + VOX;        // [VOX] winner global (in-bounds, voxel-gated)
    int* w_tgt = w_glb + VOX;        // [VOX] winner target

    const int T = 256;
    auto blocks = [](int n) { return (n + 255) / 256; };

    // 1: winner init to -1 + coords copy
    k_init<<<blocks(NV4_WS + N_COORD4), T, 0, stream>>>(
        (int*)d_ws, cur_coords, out + OFF_COORDS);

    // 2: point atomics ∥ dense default fill (disjoint memory, one dispatch)
    k_work<<<blocks(WORK_TOTAL), T, 0, stream>>>(
        cur_coords, tgt_coords_g, tgt_coords_l, glb_coords, rel_origin,
        w_cur, w_tgt, w_glb, out + OFF_VALIDT,
        out + OFF_CURVOL, out + OFF_TGTVOL);

    // 3: winner-overwrite payload + valid
    k_payload<<<blocks(PAYLOAD_TOTAL), T, 0, stream>>>(
        w_cur, w_glb, w_tgt, cur_coords, glb_coords, tgt_coords_g, tgt_coords_l,
        rel_origin, cur_values, glb_values, tgt_tsdf_g, tgt_tsdf_l,
        out + OFF_CURVOL, out + OFF_GLBVOL, out + OFF_TGTVOL, out + OFF_VALID);
}